// Round 12
// baseline (251.561 us; speedup 1.0000x reference)
//
#include <hip/hip_runtime.h>

namespace {

constexpr int LEN   = 160;
constexpr int PLANE = LEN * LEN;            // 25600
constexpr int VOL   = LEN * PLANE;          // 4,096,000 per batch
constexpr float INV_SZ = 1.0f / 125.0f;
constexpr float EPS_   = 1e-10f;

constexpr int BLK = 512;

// Both kernels: 32x16 tile, ZC=16 -> 1000 blocks (8x125, exact swizzle)
constexpr int TX = 32, TY = 16, ZC = 16;
constexpr int RX = TX + 4, RY = TY + 4;     // 36, 20
constexpr int NS = RX * RY;                 // 720 staging slots
constexpr int NBX = 5, NBY = 10, NXY = 50, NCHZ = 10;

__device__ __forceinline__ int clampi(int v) {
  return v < 0 ? 0 : (v > LEN - 1 ? LEN - 1 : v);
}

// XCD swizzle: 1000 = 8 x 125, bijective. Perf-only (R2: FETCH 112->48 MB).
struct BlkInfo { int x0, y0, z0; size_t base; };
__device__ __forceinline__ BlkInfo decodeBlock() {
  const int g = blockIdx.x + NBX * (blockIdx.y + NBY * blockIdx.z);
  const int w = (g & 7) * 125 + (g >> 3);
  const int half = NXY * NCHZ;              // 500 per batch
  const int batch = w / half, rem = w % half;
  const int zc = rem / NXY, tl = rem % NXY;
  BlkInfo bi;
  bi.x0 = (tl % NBX) * TX;
  bi.y0 = (tl / NBX) * TY;
  bi.z0 = zc * ZC;
  bi.base = (size_t)batch * VOL;
  return bi;
}

// ---------------------------------------------------------------------------
// R12 fuseAB: z-FIRST separability. Each staging thread keeps a 5-deep
// register ring of its raw px (F,M) and emits zs={SF,SM,SF2,SM2} per plane
// -> no z-rings/cen-rings/bs-adds on the output side; y = one 5-row sum.
// All LDS b128 via array-interleaved layouts zs[720][4], xz[20][32][4].
// 3 barriers/plane (R10: barrier count ~free). Ledger: only instruction-count
// cuts ever won (R6/R8/R9); this deletes ~50% of per-plane instructions.
// ---------------------------------------------------------------------------
__global__ __launch_bounds__(BLK) void fuseAB(const float* __restrict__ inA,
                                              const float* __restrict__ inB,
                                              float* __restrict__ outP) {
  __shared__ __align__(16) float zs[NS][4];        // 11.52 KB
  __shared__ __align__(16) float xz[RY][TX][4];    // 10.24 KB
  __shared__ __align__(16) float cen[TY * TX][2];  //  4.10 KB

  const int tid = threadIdx.x;
  const BlkInfo bi = decodeBlock();
  const int x0 = bi.x0, y0 = bi.y0, z0 = bi.z0;
  const size_t base = bi.base;

  // staging slots: slot0 = tid; slot1 = tid + 512 (tid < 208)
  const bool act1 = tid < (NS - BLK);
  int off[2]; float* zdst[2]; float* cdst[2]; bool isc[2];
#pragma unroll
  for (int k = 0; k < 2; ++k) {
    const int s = (k == 0) ? tid : (act1 ? tid + BLK : 0);
    const int ry = s / RX, rx = s % RX;
    off[k]  = clampi(y0 - 2 + ry) * LEN + clampi(x0 - 2 + rx);
    zdst[k] = &zs[s][0];
    isc[k]  = (rx >= 2 && rx < RX - 2 && ry >= 2 && ry < RY - 2);
    cdst[k] = isc[k] ? &cen[(ry - 2) * TX + (rx - 2)][0] : &cen[0][0];
  }

  // x-tasks on threads 352..511 (single-slot stagers): 160 tasks
  const int xt = tid - 352;
  const bool xact = xt >= 0;
  const float* xsrc = xact ? &zs[(xt >> 3) * RX + (xt & 7) * 4][0] : &zs[0][0];
  float* xdst = xact ? &xz[xt >> 3][(xt & 7) * 4][0] : &xz[0][0][0];

  // y/emit: 1 px per thread
  const int yr = tid >> 5, xc = tid & 31;
  const int sOff = (y0 + yr) * LEN + (x0 + xc);

  float rF[2][5], rM[2][5];   // z register rings
  float pfF[2], pfM[2];       // prefetch (plane c+2 at iter c)

  // prologue: ring[1..4] = raw(z0-2 .. z0+1); pf = raw(z0+2)
#pragma unroll
  for (int j = 1; j < 5; ++j) {
    const size_t pb = base + (size_t)clampi(z0 - 3 + j) * PLANE;
    rF[0][j] = inA[pb + off[0]]; rM[0][j] = inB[pb + off[0]];
    if (act1) { rF[1][j] = inA[pb + off[1]]; rM[1][j] = inB[pb + off[1]]; }
  }
  {
    const size_t pb = base + (size_t)clampi(z0 + 2) * PLANE;
    pfF[0] = inA[pb + off[0]]; pfM[0] = inB[pb + off[0]];
    if (act1) { pfF[1] = inA[pb + off[1]]; pfM[1] = inB[pb + off[1]]; }
  }

  for (int c = z0; c < z0 + ZC; ++c) {
    // ---- S0: ring push, zs + cen write, next prefetch ----
#pragma unroll
    for (int k = 0; k < 2; ++k) {
      if (k == 1 && !act1) break;
#pragma unroll
      for (int j = 0; j < 4; ++j) { rF[k][j] = rF[k][j + 1]; rM[k][j] = rM[k][j + 1]; }
      rF[k][4] = pfF[k]; rM[k][4] = pfM[k];
      const float f0 = rF[k][0], f1 = rF[k][1], f2 = rF[k][2], f3 = rF[k][3], f4 = rF[k][4];
      const float m0 = rM[k][0], m1 = rM[k][1], m2 = rM[k][2], m3 = rM[k][3], m4 = rM[k][4];
      float4 o;
      o.x = ((f0 + f1) + (f2 + f3)) + f4;
      o.y = ((m0 + m1) + (m2 + m3)) + m4;
      o.z = ((f0 * f0 + f1 * f1) + (f2 * f2 + f3 * f3)) + f4 * f4;
      o.w = ((m0 * m0 + m1 * m1) + (m2 * m2 + m3 * m3)) + m4 * m4;
      *(float4*)zdst[k] = o;
      if (isc[k]) { float2 cc; cc.x = f2; cc.y = m2; *(float2*)cdst[k] = cc; }
    }
    if (c + 3 <= z0 + ZC + 1) {
      const size_t pb = base + (size_t)clampi(c + 3) * PLANE;
      pfF[0] = inA[pb + off[0]]; pfM[0] = inB[pb + off[0]];
      if (act1) { pfF[1] = inA[pb + off[1]]; pfM[1] = inB[pb + off[1]]; }
    }
    __syncthreads();                 // zs, cen ready

    // ---- S1: sliding x-sums over slots (all 4 arrays per b128) ----
    if (xact) {
      float4 v0 = *(const float4*)(xsrc + 0);
      float4 v1 = *(const float4*)(xsrc + 4);
      float4 v2 = *(const float4*)(xsrc + 8);
      float4 v3 = *(const float4*)(xsrc + 12);
      float4 v4 = *(const float4*)(xsrc + 16);
      float4 v5 = *(const float4*)(xsrc + 20);
      float4 v6 = *(const float4*)(xsrc + 24);
      float4 v7 = *(const float4*)(xsrc + 28);
      float4 m, o0, o1, o2, o3;
      m.x = v1.x + v2.x + v3.x; m.y = v1.y + v2.y + v3.y;
      m.z = v1.z + v2.z + v3.z; m.w = v1.w + v2.w + v3.w;
      o0.x = m.x + v0.x + v4.x; o0.y = m.y + v0.y + v4.y;
      o0.z = m.z + v0.z + v4.z; o0.w = m.w + v0.w + v4.w;
      o1.x = o0.x - v0.x + v5.x; o1.y = o0.y - v0.y + v5.y;
      o1.z = o0.z - v0.z + v5.z; o1.w = o0.w - v0.w + v5.w;
      o2.x = o1.x - v1.x + v6.x; o2.y = o1.y - v1.y + v6.y;
      o2.z = o1.z - v1.z + v6.z; o2.w = o1.w - v1.w + v6.w;
      o3.x = o2.x - v2.x + v7.x; o3.y = o2.y - v2.y + v7.y;
      o3.z = o2.z - v2.z + v7.z; o3.w = o2.w - v2.w + v7.w;
      *(float4*)(xdst + 0)  = o0;
      *(float4*)(xdst + 4)  = o1;
      *(float4*)(xdst + 8)  = o2;
      *(float4*)(xdst + 12) = o3;
    }
    __syncthreads();                 // xz ready

    // ---- S2: 5-row y-sum + emit ----
    {
      float4 b = *(const float4*)&xz[yr + 0][xc][0];
#pragma unroll
      for (int k = 1; k < 5; ++k) {
        const float4 a = *(const float4*)&xz[yr + k][xc][0];
        b.x += a.x; b.y += a.y; b.z += a.z; b.w += a.w;
      }
      const float2 cc = *(const float2*)&cen[tid][0];
      const float uF = b.x * INV_SZ, uM = b.y * INV_SZ;
      const float vF = fmaxf(b.z * INV_SZ - uF * uF, 0.f);
      const float vM = fmaxf(b.w * INV_SZ - uM * uM, 0.f);
      const float o = ((cc.x - uF) * (cc.y - uM)) /
                      ((sqrtf(vF) + EPS_) * (sqrtf(vM) + EPS_));
      outP[base + (size_t)c * PLANE + sOff] = o;
    }
    __syncthreads();                 // consumption done; zs/xz/cen reusable
  }
}

// ---------------------------------------------------------------------------
// R12 slab1: z-first, single array. cross = box3(p); acc += cross^2 * mask.
// ---------------------------------------------------------------------------
__global__ __launch_bounds__(BLK) void slab1_reduce(const float* __restrict__ p,
                                                    const float* __restrict__ mask,
                                                    float* __restrict__ out) {
  __shared__ __align__(16) float zs[NS];           // 2.88 KB
  __shared__ __align__(16) float xz[RY][TX];       // 2.56 KB
  __shared__ float wsum[BLK / 64];

  const int tid = threadIdx.x;
  const BlkInfo bi = decodeBlock();
  const int x0 = bi.x0, y0 = bi.y0, z0 = bi.z0;
  const size_t base = bi.base;

  const bool act1 = tid < (NS - BLK);
  int off[2]; float* zdst[2];
#pragma unroll
  for (int k = 0; k < 2; ++k) {
    const int s = (k == 0) ? tid : (act1 ? tid + BLK : 0);
    const int ry = s / RX, rx = s % RX;
    off[k]  = clampi(y0 - 2 + ry) * LEN + clampi(x0 - 2 + rx);
    zdst[k] = &zs[s];
  }

  const int xt = tid - 352;
  const bool xact = xt >= 0;
  const float* xsrc = xact ? &zs[(xt >> 3) * RX + (xt & 7) * 4] : &zs[0];
  float* xdst = xact ? &xz[xt >> 3][(xt & 7) * 4] : &xz[0][0];

  const int yr = tid >> 5, xc = tid & 31;
  const int sOff = (y0 + yr) * LEN + (x0 + xc);

  float rp[2][5], pf[2];
  float acc = 0.f;

#pragma unroll
  for (int j = 1; j < 5; ++j) {
    const size_t pb = base + (size_t)clampi(z0 - 3 + j) * PLANE;
    rp[0][j] = p[pb + off[0]];
    if (act1) rp[1][j] = p[pb + off[1]];
  }
  {
    const size_t pb = base + (size_t)clampi(z0 + 2) * PLANE;
    pf[0] = p[pb + off[0]];
    if (act1) pf[1] = p[pb + off[1]];
  }

  for (int c = z0; c < z0 + ZC; ++c) {
#pragma unroll
    for (int k = 0; k < 2; ++k) {
      if (k == 1 && !act1) break;
#pragma unroll
      for (int j = 0; j < 4; ++j) rp[k][j] = rp[k][j + 1];
      rp[k][4] = pf[k];
      *zdst[k] = ((rp[k][0] + rp[k][1]) + (rp[k][2] + rp[k][3])) + rp[k][4];
    }
    if (c + 3 <= z0 + ZC + 1) {
      const size_t pb = base + (size_t)clampi(c + 3) * PLANE;
      pf[0] = p[pb + off[0]];
      if (act1) pf[1] = p[pb + off[1]];
    }
    __syncthreads();

    if (xact) {
      const float4 u = *(const float4*)xsrc;
      const float4 v = *(const float4*)(xsrc + 4);
      const float m = u.y + u.z + u.w;
      float4 s;
      s.x = m + u.x + v.x;
      s.y = m + v.x + v.y;
      s.z = s.y - u.y + v.z;
      s.w = s.z - u.z + v.w;
      *(float4*)xdst = s;
    }
    __syncthreads();

    {
      float bs = xz[yr + 0][xc];
#pragma unroll
      for (int k = 1; k < 5; ++k) bs += xz[yr + k][xc];
      const float mk = mask[base + (size_t)c * PLANE + sOff];
      acc += bs * bs * mk;
    }
    __syncthreads();
  }

#pragma unroll
  for (int o = 32; o > 0; o >>= 1) acc += __shfl_down(acc, o, 64);
  const int lane = tid & 63, wid = tid >> 6;
  if (lane == 0) wsum[wid] = acc;
  __syncthreads();
  if (tid == 0) {
    float tt = 0.f;
#pragma unroll
    for (int ww = 0; ww < BLK / 64; ++ww) tt += wsum[ww];
    atomicAdd(out, -tt);
  }
}

}  // namespace

extern "C" void kernel_launch(void* const* d_in, const int* in_sizes, int n_in,
                              void* d_out, int out_size, void* d_ws, size_t ws_size,
                              hipStream_t stream) {
  const float* F    = (const float*)d_in[0];
  const float* M    = (const float*)d_in[1];
  const float* mask = (const float*)d_in[2];
  float* out = (float*)d_out;

  float* pB = (float*)d_ws;   // 2*VOL floats = 32.8 MB

  hipMemsetAsync(d_out, 0, sizeof(float), stream);

  dim3 grd(NBX, NBY, NCHZ * 2), blk(BLK);   // 1000 blocks each

  fuseAB<<<grd, blk, 0, stream>>>(F, M, pB);
  slab1_reduce<<<grd, blk, 0, stream>>>(pB, mask, out);
}

// Round 13
// 180.966 us; speedup vs baseline: 1.3901x; 1.3901x over previous
//
#include <hip/hip_runtime.h>

namespace {

constexpr int LEN   = 160;
constexpr int PLANE = LEN * LEN;            // 25600
constexpr int VOL   = LEN * PLANE;          // 4,096,000 per batch
constexpr float INV_SZ = 1.0f / 125.0f;
constexpr float EPS_   = 1e-10f;

constexpr int BLK = 512;
constexpr int TX = 32, TY = 16, ZC = 16;    // 1000 blocks (8x125 swizzle)
constexpr int RX = TX + 4, RY = TY + 4;     // 36, 20
constexpr int NS = RX * RY;                 // 720 staging slots
constexpr int SP  = 37;                     // fuseAB zs slot-row stride (float4)
constexpr int SP1 = 40;                     // slab1 zs slot-row stride (float, 16B-aligned)
constexpr int NBX = 5, NBY = 10, NXY = 50, NCHZ = 10;

__device__ __forceinline__ int clampi(int v) {
  return v < 0 ? 0 : (v > LEN - 1 ? LEN - 1 : v);
}

// XCD swizzle: 1000 = 8 x 125, bijective. Perf-only (R2: FETCH 112->48 MB).
struct BlkInfo { int x0, y0, z0; size_t base; };
__device__ __forceinline__ BlkInfo decodeBlock() {
  const int g = blockIdx.x + NBX * (blockIdx.y + NBY * blockIdx.z);
  const int w = (g & 7) * 125 + (g >> 3);
  const int half = NXY * NCHZ;              // 500 per batch
  const int batch = w / half, rem = w % half;
  const int zc = rem / NXY, tl = rem % NXY;
  BlkInfo bi;
  bi.x0 = (tl % NBX) * TX;
  bi.y0 = (tl / NBX) * TY;
  bi.z0 = zc * ZC;
  bi.base = (size_t)batch * VOL;
  return bi;
}

// ---------------------------------------------------------------------------
// R13 fuseAB: z-first algebra (R12) on the pair-pipelined 2-barrier skeleton
// (R6/R11-proven granularity: 1 barrier/plane; R12's 3/plane was the 2.6x
// regression). P1: stagers push 6-deep reg ring, write zs[buf] (centers
// t,t+1; one b128/plane/slot), cen (planes t-2,t-1; single-buffer, read
// across bar); x-tasks slide zs[buf^1] -> xz. P2: consumers 5xb128 y-sum +
// emit. Consumer ring machinery from R11 (96 ring floats + shifts + bs-adds)
// is deleted entirely.
// ---------------------------------------------------------------------------
__global__ __launch_bounds__(BLK) void fuseAB(const float* __restrict__ inA,
                                              const float* __restrict__ inB,
                                              float* __restrict__ outP,
                                              float* __restrict__ out0) {
  __shared__ __align__(16) float4 zs[2][2][RY * SP];   // [buf][plane] 47.4 KB
  __shared__ __align__(16) float4 xz[2][RY][TX + 1];   // [plane][row] 21.1 KB
  __shared__ __align__(16) float4 cen[TY * TX];        // 8.2 KB

  const int tid = threadIdx.x;
  const BlkInfo bi = decodeBlock();
  const int x0 = bi.x0, y0 = bi.y0, z0 = bi.z0;
  const size_t base = bi.base;

  if (blockIdx.x == 0 && blockIdx.y == 0 && blockIdx.z == 0 && tid == 0)
    *out0 = 0.f;   // replaces the memset dispatch (runs before slab1)

  // staging slots: slot0 = tid; slot1 = tid + 512 (tid < 208)
  const bool act1 = tid < (NS - BLK);
  int off[2], ps[2], cpx[2]; bool isc[2];
#pragma unroll
  for (int k = 0; k < 2; ++k) {
    const int s = (k == 0) ? tid : (act1 ? tid + BLK : 0);
    const int ry = s / RX, rx = s % RX;
    off[k] = clampi(y0 - 2 + ry) * LEN + clampi(x0 - 2 + rx);
    ps[k]  = ry * SP + rx;
    isc[k] = (rx >= 2 && rx < RX - 2 && ry >= 2 && ry < RY - 2);
    cpx[k] = isc[k] ? (ry - 2) * TX + (rx - 2) : 0;
  }

  // x-tasks: tid 192..511 -> 320 tasks (plane, row, 4-col group)
  const bool xact = tid >= 192;
  const int xt = xact ? tid - 192 : 0;
  const int xp = xt / 160, xr1 = xt % 160;
  const int xr = xr1 >> 3, xc4 = xr1 & 7;
  const int xsrcOff = xr * SP + 4 * xc4;   // within zs[buf^1][xp]

  // consumers: 1 px each
  const int yr = tid >> 5, xcc = tid & 31;
  const int sOff = (y0 + yr) * LEN + (x0 + xcc);

  float rF[2][6], rM[2][6];     // 6-deep z register rings
  float pfF[2][2], pfM[2][2];   // prefetch (planes t+4, t+5)

  auto loadPF = [&](int t4) {
#pragma unroll
    for (int p = 0; p < 2; ++p) {
      const size_t pb = base + (size_t)clampi(t4 + p) * PLANE;
      pfF[0][p] = inA[pb + off[0]]; pfM[0][p] = inB[pb + off[0]];
      if (act1) { pfF[1][p] = inA[pb + off[1]]; pfM[1][p] = inB[pb + off[1]]; }
    }
  };
  // compute + write zs[buf] for centers (c0, c0+1) from ring entries 0..5
  auto writeZS = [&](int buf) {
#pragma unroll
    for (int k = 0; k < 2; ++k) {
      if (k == 1 && !act1) break;
      const float f0 = rF[k][0], f1 = rF[k][1], f2 = rF[k][2];
      const float f3 = rF[k][3], f4 = rF[k][4], f5 = rF[k][5];
      const float m0 = rM[k][0], m1 = rM[k][1], m2 = rM[k][2];
      const float m3 = rM[k][3], m4 = rM[k][4], m5 = rM[k][5];
      const float mf = (f1 + f2) + (f3 + f4), mm = (m1 + m2) + (m3 + m4);
      const float g0 = f0 * f0, g1 = f1 * f1, g2 = f2 * f2;
      const float g3 = f3 * f3, g4 = f4 * f4, g5 = f5 * f5;
      const float h0 = m0 * m0, h1 = m1 * m1, h2 = m2 * m2;
      const float h3 = m3 * m3, h4 = m4 * m4, h5 = m5 * m5;
      const float mg = (g1 + g2) + (g3 + g4), mh = (h1 + h2) + (h3 + h4);
      float4 a, b;
      a.x = mf + f0; a.y = mm + m0; a.z = mg + g0; a.w = mh + h0;
      b.x = mf + f5; b.y = mm + m5; b.z = mg + g5; b.w = mh + h5;
      zs[buf][0][ps[k]] = a;
      zs[buf][1][ps[k]] = b;
    }
  };

  // ---- prologue: ring <- planes z0-2..z0+3; zs[0] centers (z0, z0+1) ----
#pragma unroll
  for (int j = 0; j < 6; ++j) {
    const size_t pb = base + (size_t)clampi(z0 - 2 + j) * PLANE;
    rF[0][j] = inA[pb + off[0]]; rM[0][j] = inB[pb + off[0]];
    if (act1) { rF[1][j] = inA[pb + off[1]]; rM[1][j] = inB[pb + off[1]]; }
  }
  writeZS(0);
  loadPF(z0 + 4);
  __syncthreads();

  // ---- body: 2 barriers per pair-iter (1/plane) ----
  auto body = [&](int buf, int t) {
    // P1: shift ring by 2, push prefetched pair (t+2, t+3)
#pragma unroll
    for (int k = 0; k < 2; ++k) {
      if (k == 1 && !act1) break;
#pragma unroll
      for (int j = 0; j < 4; ++j) { rF[k][j] = rF[k][j + 2]; rM[k][j] = rM[k][j + 2]; }
      rF[k][4] = pfF[k][0]; rF[k][5] = pfF[k][1];
      rM[k][4] = pfM[k][0]; rM[k][5] = pfM[k][1];
    }
    if (t <= z0 + ZC - 2) writeZS(buf);   // centers (t, t+1); unread past that
    // cen for the planes emitted THIS iter: t-2 = ring[0], t-1 = ring[1]
#pragma unroll
    for (int k = 0; k < 2; ++k) {
      if (k == 1 && !act1) break;
      if (isc[k]) {
        float4 cc;
        cc.x = rF[k][0]; cc.y = rM[k][0]; cc.z = rF[k][1]; cc.w = rM[k][1];
        cen[cpx[k]] = cc;
      }
    }
    if (t <= z0 + ZC - 4) loadPF(t + 4);  // feeds body(t+2)'s zs

    if (xact) {   // slide zs[buf^1] (centers t-2, t-1) -> xz
      const float4* s = &zs[buf ^ 1][xp][xsrcOff];
      const float4 v0 = s[0], v1 = s[1], v2 = s[2], v3 = s[3];
      const float4 v4 = s[4], v5 = s[5], v6 = s[6], v7 = s[7];
      float4 m, o0, o1, o2, o3;
      m.x = v1.x + v2.x + v3.x; m.y = v1.y + v2.y + v3.y;
      m.z = v1.z + v2.z + v3.z; m.w = v1.w + v2.w + v3.w;
      o0.x = m.x + v0.x + v4.x; o0.y = m.y + v0.y + v4.y;
      o0.z = m.z + v0.z + v4.z; o0.w = m.w + v0.w + v4.w;
      o1.x = o0.x - v0.x + v5.x; o1.y = o0.y - v0.y + v5.y;
      o1.z = o0.z - v0.z + v5.z; o1.w = o0.w - v0.w + v5.w;
      o2.x = o1.x - v1.x + v6.x; o2.y = o1.y - v1.y + v6.y;
      o2.z = o1.z - v1.z + v6.z; o2.w = o1.w - v1.w + v6.w;
      o3.x = o2.x - v2.x + v7.x; o3.y = o2.y - v2.y + v7.y;
      o3.z = o2.z - v2.z + v7.z; o3.w = o2.w - v2.w + v7.w;
      float4* d = &xz[xp][xr][4 * xc4];
      d[0] = o0; d[1] = o1; d[2] = o2; d[3] = o3;
    }
    __syncthreads();   // zs/cen/xz ready

    // P2: consumers emit planes (t-2, t-1)
    const float4 cc = cen[tid];
#pragma unroll
    for (int q = 0; q < 2; ++q) {
      float4 b = xz[q][yr][xcc];
#pragma unroll
      for (int k = 1; k < 5; ++k) {
        const float4 a = xz[q][yr + k][xcc];
        b.x += a.x; b.y += a.y; b.z += a.z; b.w += a.w;
      }
      const float cF = (q == 0) ? cc.x : cc.z;
      const float cM = (q == 0) ? cc.y : cc.w;
      const float uF = b.x * INV_SZ, uM = b.y * INV_SZ;
      const float vF = fmaxf(b.z * INV_SZ - uF * uF, 0.f);
      const float vM = fmaxf(b.w * INV_SZ - uM * uM, 0.f);
      const float o = ((cF - uF) * (cM - uM)) /
                      ((sqrtf(vF) + EPS_) * (sqrtf(vM) + EPS_));
      outP[base + (size_t)(t - 2 + q) * PLANE + sOff] = o;
    }
    __syncthreads();   // consumption done; cen/xz reusable next iter
  };

  // 8 pair-iters, unrolled x2 for compile-time buf (first body buf=1)
  for (int t = z0 + 2; t <= z0 + ZC; t += 4) {
    body(1, t);
    body(0, t + 2);
  }
}

// ---------------------------------------------------------------------------
// R13 slab1: same skeleton, single field. cross = box3(p);
// acc += cross^2 * mask; block reduce -> atomicAdd.
// ---------------------------------------------------------------------------
__global__ __launch_bounds__(BLK) void slab1_reduce(const float* __restrict__ p,
                                                    const float* __restrict__ mask,
                                                    float* __restrict__ out) {
  __shared__ __align__(16) float zs1[2][2][RY * SP1];  // 12.8 KB
  __shared__ __align__(16) float xz1[RY][TX + 1][2];   // 5.3 KB
  __shared__ float wsum[BLK / 64];

  const int tid = threadIdx.x;
  const BlkInfo bi = decodeBlock();
  const int x0 = bi.x0, y0 = bi.y0, z0 = bi.z0;
  const size_t base = bi.base;

  const bool act1 = tid < (NS - BLK);
  int off[2], ps[2];
#pragma unroll
  for (int k = 0; k < 2; ++k) {
    const int s = (k == 0) ? tid : (act1 ? tid + BLK : 0);
    const int ry = s / RX, rx = s % RX;
    off[k] = clampi(y0 - 2 + ry) * LEN + clampi(x0 - 2 + rx);
    ps[k]  = ry * SP1 + rx;
  }

  const bool xact = tid >= 192;
  const int xt = xact ? tid - 192 : 0;
  const int xp = xt / 160, xr1 = xt % 160;
  const int xr = xr1 >> 3, xc4 = xr1 & 7;
  const int xsrcOff = xr * SP1 + 4 * xc4;

  const int yr = tid >> 5, xcc = tid & 31;
  const int sOff = (y0 + yr) * LEN + (x0 + xcc);

  float rp[2][6], pf[2][2];
  float acc = 0.f;

  auto loadPF = [&](int t4) {
#pragma unroll
    for (int q = 0; q < 2; ++q) {
      const size_t pb = base + (size_t)clampi(t4 + q) * PLANE;
      pf[0][q] = p[pb + off[0]];
      if (act1) pf[1][q] = p[pb + off[1]];
    }
  };
  auto writeZS = [&](int buf) {
#pragma unroll
    for (int k = 0; k < 2; ++k) {
      if (k == 1 && !act1) break;
      const float m = (rp[k][1] + rp[k][2]) + (rp[k][3] + rp[k][4]);
      zs1[buf][0][ps[k]] = m + rp[k][0];
      zs1[buf][1][ps[k]] = m + rp[k][5];
    }
  };

#pragma unroll
  for (int j = 0; j < 6; ++j) {
    const size_t pb = base + (size_t)clampi(z0 - 2 + j) * PLANE;
    rp[0][j] = p[pb + off[0]];
    if (act1) rp[1][j] = p[pb + off[1]];
  }
  writeZS(0);
  loadPF(z0 + 4);
  __syncthreads();

  auto body = [&](int buf, int t) {
#pragma unroll
    for (int k = 0; k < 2; ++k) {
      if (k == 1 && !act1) break;
#pragma unroll
      for (int j = 0; j < 4; ++j) rp[k][j] = rp[k][j + 2];
      rp[k][4] = pf[k][0]; rp[k][5] = pf[k][1];
    }
    if (t <= z0 + ZC - 2) writeZS(buf);
    if (t <= z0 + ZC - 4) loadPF(t + 4);

    if (xact) {
      const float* s = &zs1[buf ^ 1][xp][xsrcOff];
      const float4 u = *(const float4*)s;
      const float4 v = *(const float4*)(s + 4);
      const float m = u.y + u.z + u.w;
      float o0 = m + u.x + v.x;
      float o1 = o0 - u.x + v.y;
      float o2 = o1 - u.y + v.z;
      float o3 = o2 - u.z + v.w;
      xz1[xr][4 * xc4 + 0][xp] = o0;
      xz1[xr][4 * xc4 + 1][xp] = o1;
      xz1[xr][4 * xc4 + 2][xp] = o2;
      xz1[xr][4 * xc4 + 3][xp] = o3;
    }
    __syncthreads();

    {
      float2 b = *(const float2*)&xz1[yr][xcc][0];
#pragma unroll
      for (int k = 1; k < 5; ++k) {
        const float2 a = *(const float2*)&xz1[yr + k][xcc][0];
        b.x += a.x; b.y += a.y;
      }
      const size_t g0 = base + (size_t)(t - 2) * PLANE + sOff;
      acc += b.x * b.x * mask[g0];
      acc += b.y * b.y * mask[g0 + PLANE];
    }
    __syncthreads();
  };

  for (int t = z0 + 2; t <= z0 + ZC; t += 4) {
    body(1, t);
    body(0, t + 2);
  }

#pragma unroll
  for (int o = 32; o > 0; o >>= 1) acc += __shfl_down(acc, o, 64);
  const int lane = tid & 63, wid = tid >> 6;
  if (lane == 0) wsum[wid] = acc;
  __syncthreads();
  if (tid == 0) {
    float tt = 0.f;
#pragma unroll
    for (int ww = 0; ww < BLK / 64; ++ww) tt += wsum[ww];
    atomicAdd(out, -tt);
  }
}

}  // namespace

extern "C" void kernel_launch(void* const* d_in, const int* in_sizes, int n_in,
                              void* d_out, int out_size, void* d_ws, size_t ws_size,
                              hipStream_t stream) {
  const float* F    = (const float*)d_in[0];
  const float* M    = (const float*)d_in[1];
  const float* mask = (const float*)d_in[2];
  float* out = (float*)d_out;

  float* pB = (float*)d_ws;   // 2*VOL floats = 32.8 MB

  dim3 grd(NBX, NBY, NCHZ * 2), blk(BLK);   // 1000 blocks each

  fuseAB<<<grd, blk, 0, stream>>>(F, M, pB, out);   // also zeroes out
  slab1_reduce<<<grd, blk, 0, stream>>>(pB, mask, out);
}